// Round 13
// baseline (25.806 us; speedup 1.0000x reference)
//
#include <hip/hip_runtime.h>

// VectorGauntTensorProduct — factored algebraic collapse, 2-launch structure.
// r13 = r11 structure (separate A/B stages, Z buffer, Zout overlay on Ts) with
// LDS-instruction-minimizing thread mappings:
//   A': thread=(t, row-triple): 50 threads, T-chunk loaded once per 3 rows.
//   B': thread=(row,lt,dq): 240 threads, 9 V-f4 hoisted once, 3 Z-reads/t.
//
// T[t,pq]  = sum_g wq[g] Yin[g,s] Yin[g,sp] Yout[g,t]       (25x100, block-padded)
// V[lt,b,d]= sum_c Wx[ls,c] Wy[lsp,c] Wz[lt,c,d]            (stride-292 rows)
// P[row,pq]= x[n,a,s] y[n,b,sp] - x[n,b,s] y[n,a,sp]        (row = ni*3+v)
// Z[row,t,b] = sum_{pq in block b} P[row,pq] T[t,pq]
// out[n,d,v,t] = sum_b Z[row,t,b] V[l(t),b,d]
//
// Padded block layout: b = ls*3+lsp, real sizes {1,3,5,3,9,15,5,15,25} padded
// to {4,4,8,4,12,16,8,16,28}, starts {0,4,8,16,20,32,48,56,72}, total 100.
// Pads are 0.0 in BOTH T and P. V stride 292 de-aliases lt bank groups.
//
// BUG HISTORY: r4 overlay race; r4-r6 `if(tid<N)` staging bug (STRIDED loops
// only). r9->r10: no direct scatter stores (L2 sector amplification) — stage
// in LDS, store coalesced f4. r10->r11: LDS <= 40KB keeps 4 blocks/CU.
// r12 lesson: cutting LDS *data* while adding LDS *instructions* regresses —
// optimize wave-instruction count, not bytes.

#define GG 380

__device__ __forceinline__ bool decode2(int pq, int& s, int& sp) {
    int b, off;
    if (pq < 16) {
        if (pq < 4)       { b = 0; off = pq; }
        else if (pq < 8)  { b = 1; off = pq - 4; }
        else              { b = 2; off = pq - 8; }
    } else if (pq < 48) {
        if (pq < 20)      { b = 3; off = pq - 16; }
        else if (pq < 32) { b = 4; off = pq - 20; }
        else              { b = 5; off = pq - 32; }
    } else {
        if (pq < 56)      { b = 6; off = pq - 48; }
        else if (pq < 72) { b = 7; off = pq - 56; }
        else              { b = 8; off = pq - 72; }
    }
    int ls = b / 3, lsp = b % 3, w = 2 * lsp + 1;
    if (off >= (2 * ls + 1) * w) return false;
    s  = ls * ls + off / w;
    sp = lsp * lsp + off % w;
    return true;
}

// ---- precomp: T wave-per-entry + V stride-292 (r12-proven, unchanged)
__global__ __launch_bounds__(256) void precomp(const float* __restrict__ Wx,
                                               const float* __restrict__ Wy,
                                               const float* __restrict__ Wz,
                                               const float* __restrict__ Yin,
                                               const float* __restrict__ Yout,
                                               const float* __restrict__ wq,
                                               float* __restrict__ Tg,
                                               float* __restrict__ Vg) {
    int bid = blockIdx.x;
    if (bid < 625) {
        int W = bid * 4 + (threadIdx.x >> 6);     // 0..2499, = t*100 + pq
        int lane = threadIdx.x & 63;
        int t = W / 100, pq = W % 100;
        int s, sp;
        float acc = 0.f;
        if (decode2(pq, s, sp)) {
#pragma unroll
            for (int i = 0; i < 6; ++i) {
                int g = lane + 64 * i;
                if (g < GG)
                    acc = fmaf(wq[g] * Yin[g * 9 + s],
                               Yin[g * 9 + sp] * Yout[g * 25 + t], acc);
            }
        }
#pragma unroll
        for (int m = 32; m; m >>= 1) acc += __shfl_xor(acc, m, 64);
        if (lane == 0) Tg[W] = acc;               // pads write 0
    } else {
        int idx = (bid - 625) * 256 + threadIdx.x;
        if (idx < 1460) {                          // 5 rows * 292 (incl pads)
            int lt = idx / 292, r = idx % 292;
            float acc = 0.f;
            if (r < 288) {
                int b = r / 32, d = r % 32;
                int ls = b / 3, lsp = b % 3;
                for (int c = 0; c < 32; ++c)
                    acc = fmaf(Wx[ls * 32 + c] * Wy[lsp * 32 + c],
                               Wz[lt * 1024 + c * 32 + d], acc);
            }
            Vg[idx] = acc;                         // pad slots -> 0
        }
    }
}

// chunk c (0..24) -> l-block b
__device__ __constant__ const int BOFC[25] =
    {0,1,2,2,3,4,4,4,5,5,5,5,6,6,7,7,7,7,8,8,8,8,8,8,8};

// ---- main: 2 samples/block, 1024 blocks, 256 threads, LDS 35.5 KB.
// LDS floats: xs[0,108)* ys[108,216)* Ps[216,816) Vs[816,2276) Z[2276,4076)
//             Ts[4076,6576) | Zout[4076,8876) overlays Ts (dead after A).
__global__ __launch_bounds__(256) void gaunt_main(const float* __restrict__ x,
                                                  const float* __restrict__ y,
                                                  const float* __restrict__ Tg,
                                                  const float* __restrict__ Vg,
                                                  float* __restrict__ out) {
    __shared__ __align__(16) float smem[8876];
    float* xs   = smem;            // 54 used
    float* ys   = smem + 108;      // 54 used
    float* Ps   = smem + 216;      // 6*100
    float* Vs   = smem + 816;      // 5*292
    float* Z    = smem + 2276;     // 6*300
    float* Ts   = smem + 4076;     // 25*100 (dead after stage A)
    float* Zout = smem + 4076;     // 4800 (stage B + copy-out only)

    const int tid = threadIdx.x;
    const int n0 = blockIdx.x * 2;

    if (tid < 54)       xs[tid]      = x[n0 * 27 + tid];
    else if (tid < 108) ys[tid - 54] = y[n0 * 27 + tid - 54];
    for (int i = tid; i < 625; i += 256)            // Ts: 2500 floats
        ((float4*)Ts)[i] = ((const float4*)Tg)[i];
    for (int i = tid; i < 365; i += 256)            // Vs: 1460 floats (strided)
        ((float4*)Vs)[i] = ((const float4*)Vg)[i];
    __syncthreads();

    // P[row][100], pads zero
    for (int idx = tid; idx < 600; idx += 256) {
        int row = idx / 100, pq = idx % 100;
        float v = 0.f;
        int s, sp;
        if (decode2(pq, s, sp)) {
            int ni = row / 3, vv = row % 3;
            int a = (vv == 0) ? 1 : ((vv == 1) ? 2 : 0);
            int b = (vv == 0) ? 2 : ((vv == 1) ? 0 : 1);
            v = xs[ni * 27 + a * 9 + s] * ys[ni * 27 + b * 9 + sp]
              - xs[ni * 27 + b * 9 + s] * ys[ni * 27 + a * 9 + sp];
        }
        Ps[idx] = v;
    }
    __syncthreads();

    // Stage A': 50 threads, thread = (t, row-triple rh). T chunk read once,
    // reused for 3 rows. 25 T-f4 + 75 P-f4 per thread; Z written 2f4+1s per row.
    if (tid < 50) {
        const int t = tid >> 1, rh = tid & 1;
        const float4* T4 = (const float4*)(Ts + t * 100);
        const float4* Q0 = (const float4*)(Ps + (3 * rh + 0) * 100);
        const float4* Q1 = (const float4*)(Ps + (3 * rh + 1) * 100);
        const float4* Q2 = (const float4*)(Ps + (3 * rh + 2) * 100);
        float A0[9], A1[9], A2[9];
#pragma unroll
        for (int b = 0; b < 9; ++b) { A0[b] = 0.f; A1[b] = 0.f; A2[b] = 0.f; }
#pragma unroll
        for (int c = 0; c < 25; ++c) {
            const int b = BOFC[c];
            const float4 tv = T4[c];
            float4 pv;
            pv = Q0[c];
            A0[b] = fmaf(pv.x, tv.x, A0[b]); A0[b] = fmaf(pv.y, tv.y, A0[b]);
            A0[b] = fmaf(pv.z, tv.z, A0[b]); A0[b] = fmaf(pv.w, tv.w, A0[b]);
            pv = Q1[c];
            A1[b] = fmaf(pv.x, tv.x, A1[b]); A1[b] = fmaf(pv.y, tv.y, A1[b]);
            A1[b] = fmaf(pv.z, tv.z, A1[b]); A1[b] = fmaf(pv.w, tv.w, A1[b]);
            pv = Q2[c];
            A2[b] = fmaf(pv.x, tv.x, A2[b]); A2[b] = fmaf(pv.y, tv.y, A2[b]);
            A2[b] = fmaf(pv.z, tv.z, A2[b]); A2[b] = fmaf(pv.w, tv.w, A2[b]);
        }
        float* zp;
        zp = Z + (3 * rh + 0) * 300 + t * 12;
        *(float4*)zp = make_float4(A0[0], A0[1], A0[2], A0[3]);
        *(float4*)(zp + 4) = make_float4(A0[4], A0[5], A0[6], A0[7]);
        zp[8] = A0[8];
        zp = Z + (3 * rh + 1) * 300 + t * 12;
        *(float4*)zp = make_float4(A1[0], A1[1], A1[2], A1[3]);
        *(float4*)(zp + 4) = make_float4(A1[4], A1[5], A1[6], A1[7]);
        zp[8] = A1[8];
        zp = Z + (3 * rh + 2) * 300 + t * 12;
        *(float4*)zp = make_float4(A2[0], A2[1], A2[2], A2[3]);
        *(float4*)(zp + 4) = make_float4(A2[4], A2[5], A2[6], A2[7]);
        zp[8] = A2[8];
    }
    __syncthreads();
    // ---- Ts DEAD from here; Zout (overlaying it) becomes live ----

    // Stage B': 240 threads, thread = (lt = tid/48; row = (tid%48)/8; dq = tid&7).
    // 9 V-f4 hoisted once; per t: 2f4+1s Z-read (broadcast) + 36 FMA + 4 writes.
    if (tid < 240) {
        const int lt = tid / 48, r = tid % 48, row = r >> 3, dq = r & 7;
        const float* vb = Vs + lt * 292 + dq * 4;
        const float4 w0 = *(const float4*)(vb +   0);
        const float4 w1 = *(const float4*)(vb +  32);
        const float4 w2 = *(const float4*)(vb +  64);
        const float4 w3 = *(const float4*)(vb +  96);
        const float4 w4 = *(const float4*)(vb + 128);
        const float4 w5 = *(const float4*)(vb + 160);
        const float4 w6 = *(const float4*)(vb + 192);
        const float4 w7 = *(const float4*)(vb + 224);
        const float4 w8 = *(const float4*)(vb + 256);
        const int t1 = (lt + 1) * (lt + 1);
        const int zo = (row / 3) * 2400 + (row % 3) * 25 + dq * 300; // dq*4*75
        const float* zrow = Z + row * 300;
        for (int t = lt * lt; t < t1; ++t) {
            const float* zp = zrow + t * 12;
            const float4 za = *(const float4*)zp;
            const float4 zb = *(const float4*)(zp + 4);
            const float z8 = zp[8];
            float o0 = z8 * w8.x, o1 = z8 * w8.y, o2 = z8 * w8.z, o3 = z8 * w8.w;
            o0 = fmaf(za.x, w0.x, o0); o1 = fmaf(za.x, w0.y, o1);
            o2 = fmaf(za.x, w0.z, o2); o3 = fmaf(za.x, w0.w, o3);
            o0 = fmaf(za.y, w1.x, o0); o1 = fmaf(za.y, w1.y, o1);
            o2 = fmaf(za.y, w1.z, o2); o3 = fmaf(za.y, w1.w, o3);
            o0 = fmaf(za.z, w2.x, o0); o1 = fmaf(za.z, w2.y, o1);
            o2 = fmaf(za.z, w2.z, o2); o3 = fmaf(za.z, w2.w, o3);
            o0 = fmaf(za.w, w3.x, o0); o1 = fmaf(za.w, w3.y, o1);
            o2 = fmaf(za.w, w3.z, o2); o3 = fmaf(za.w, w3.w, o3);
            o0 = fmaf(zb.x, w4.x, o0); o1 = fmaf(zb.x, w4.y, o1);
            o2 = fmaf(zb.x, w4.z, o2); o3 = fmaf(zb.x, w4.w, o3);
            o0 = fmaf(zb.y, w5.x, o0); o1 = fmaf(zb.y, w5.y, o1);
            o2 = fmaf(zb.y, w5.z, o2); o3 = fmaf(zb.y, w5.w, o3);
            o0 = fmaf(zb.z, w6.x, o0); o1 = fmaf(zb.z, w6.y, o1);
            o2 = fmaf(zb.z, w6.z, o2); o3 = fmaf(zb.z, w6.w, o3);
            o0 = fmaf(zb.w, w7.x, o0); o1 = fmaf(zb.w, w7.y, o1);
            o2 = fmaf(zb.w, w7.z, o2); o3 = fmaf(zb.w, w7.w, o3);
            Zout[zo + t      ] = o0;
            Zout[zo + t +  75] = o1;
            Zout[zo + t + 150] = o2;
            Zout[zo + t + 225] = o3;
        }
    }
    __syncthreads();

    // coalesced copy-out: 4800 floats = 1200 float4, contiguous per block
    float4* og = (float4*)(out + (size_t)n0 * 2400);
    const float4* zo4 = (const float4*)Zout;
    for (int i = tid; i < 1200; i += 256) og[i] = zo4[i];
}

extern "C" void kernel_launch(void* const* d_in, const int* in_sizes, int n_in,
                              void* d_out, int out_size, void* d_ws, size_t ws_size,
                              hipStream_t stream) {
    const float* x    = (const float*)d_in[0];
    const float* y    = (const float*)d_in[1];
    const float* Wx   = (const float*)d_in[2];
    const float* Wy   = (const float*)d_in[3];
    const float* Wz   = (const float*)d_in[4];
    const float* Yin  = (const float*)d_in[5];
    const float* Yout = (const float*)d_in[6];
    const float* wq   = (const float*)d_in[7];
    float* out = (float*)d_out;

    float* Tg = (float*)d_ws;        // 25*100 = 2500 floats
    float* Vg = Tg + 2500;           // 5*292 = 1460 floats (16B-aligned)

    precomp<<<631, 256, 0, stream>>>(Wx, Wy, Wz, Yin, Yout, wq, Tg, Vg);
    gaunt_main<<<1024, 256, 0, stream>>>(x, y, Tg, Vg, out);
}

// Round 14
// 19.962 us; speedup vs baseline: 1.2927x; 1.2927x over previous
//
#include <hip/hip_runtime.h>

// VectorGauntTensorProduct — factored algebraic collapse, 2-launch structure.
// r14 = r11 + ONLY stage B remapped: thread=(t,dq), 200 threads, V-f4 hoisted,
// f4 Z-reads (conflict-free bank spans), uniform loops. Stage A = r11 verbatim.
//
// T[t,pq]  = sum_g wq[g] Yin[g,s] Yin[g,sp] Yout[g,t]       (25x100, block-padded)
// V[lt,b,d]= sum_c Wx[ls,c] Wy[lsp,c] Wz[lt,c,d]            (stride-292 rows)
// P[row,pq]= x[n,a,s] y[n,b,sp] - x[n,b,s] y[n,a,sp]        (row = ni*3+v)
// Z[row,t,b] = sum_{pq in block b} P[row,pq] T[t,pq]
// out[n,d,v,t] = sum_b Z[row,t,b] V[l(t),b,d]
//
// Padded block layout: b = ls*3+lsp, real sizes {1,3,5,3,9,15,5,15,25} padded
// to {4,4,8,4,12,16,8,16,28}, starts {0,4,8,16,20,32,48,56,72}, total 100.
// Pads are 0.0 in BOTH T and P. V stride 292 de-aliases lt bank groups.
//
// BUG HISTORY: r4 overlay race; r4-r6 `if(tid<N)` staging bug (STRIDED loops
// only). r9->r10: no direct scatter stores — stage in LDS, store coalesced f4.
// r10->r11: LDS <= 40KB keeps 4 blocks/CU. r12: cutting LDS data while adding
// LDS instructions regresses. r13: concentrating a phase into <1 wave/block
// regresses (latency chain) — keep >=3 active waves/block per phase.

#define GG 380

__device__ __forceinline__ bool decode2(int pq, int& s, int& sp) {
    int b, off;
    if (pq < 16) {
        if (pq < 4)       { b = 0; off = pq; }
        else if (pq < 8)  { b = 1; off = pq - 4; }
        else              { b = 2; off = pq - 8; }
    } else if (pq < 48) {
        if (pq < 20)      { b = 3; off = pq - 16; }
        else if (pq < 32) { b = 4; off = pq - 20; }
        else              { b = 5; off = pq - 32; }
    } else {
        if (pq < 56)      { b = 6; off = pq - 48; }
        else if (pq < 72) { b = 7; off = pq - 56; }
        else              { b = 8; off = pq - 72; }
    }
    int ls = b / 3, lsp = b % 3, w = 2 * lsp + 1;
    if (off >= (2 * ls + 1) * w) return false;
    s  = ls * ls + off / w;
    sp = lsp * lsp + off % w;
    return true;
}

// ---- precomp: T wave-per-entry + V stride-292 (r12/r13-proven, unchanged)
__global__ __launch_bounds__(256) void precomp(const float* __restrict__ Wx,
                                               const float* __restrict__ Wy,
                                               const float* __restrict__ Wz,
                                               const float* __restrict__ Yin,
                                               const float* __restrict__ Yout,
                                               const float* __restrict__ wq,
                                               float* __restrict__ Tg,
                                               float* __restrict__ Vg) {
    int bid = blockIdx.x;
    if (bid < 625) {
        int W = bid * 4 + (threadIdx.x >> 6);     // 0..2499, = t*100 + pq
        int lane = threadIdx.x & 63;
        int t = W / 100, pq = W % 100;
        int s, sp;
        float acc = 0.f;
        if (decode2(pq, s, sp)) {
#pragma unroll
            for (int i = 0; i < 6; ++i) {
                int g = lane + 64 * i;
                if (g < GG)
                    acc = fmaf(wq[g] * Yin[g * 9 + s],
                               Yin[g * 9 + sp] * Yout[g * 25 + t], acc);
            }
        }
#pragma unroll
        for (int m = 32; m; m >>= 1) acc += __shfl_xor(acc, m, 64);
        if (lane == 0) Tg[W] = acc;               // pads write 0
    } else {
        int idx = (bid - 625) * 256 + threadIdx.x;
        if (idx < 1460) {                          // 5 rows * 292 (incl pads)
            int lt = idx / 292, r = idx % 292;
            float acc = 0.f;
            if (r < 288) {
                int b = r / 32, d = r % 32;
                int ls = b / 3, lsp = b % 3;
                for (int c = 0; c < 32; ++c)
                    acc = fmaf(Wx[ls * 32 + c] * Wy[lsp * 32 + c],
                               Wz[lt * 1024 + c * 32 + d], acc);
            }
            Vg[idx] = acc;                         // pad slots -> 0
        }
    }
}

// ---- main: 2 samples/block, 1024 blocks, 256 threads, LDS 35.5 KB.
// LDS floats: xs[0,108)* ys[108,216)* Ps[216,816) Vs[816,2276) Z[2276,4076)
//             Ts[4076,6576) | Zout[4076,8876) overlays Ts (dead after A).
__global__ __launch_bounds__(256) void gaunt_main(const float* __restrict__ x,
                                                  const float* __restrict__ y,
                                                  const float* __restrict__ Tg,
                                                  const float* __restrict__ Vg,
                                                  float* __restrict__ out) {
    __shared__ __align__(16) float smem[8876];
    float* xs   = smem;            // 54 used
    float* ys   = smem + 108;      // 54 used
    float* Ps   = smem + 216;      // 6*100
    float* Vs   = smem + 816;      // 5*292
    float* Z    = smem + 2276;     // 6*300
    float* Ts   = smem + 4076;     // 25*100 (dead after stage A)
    float* Zout = smem + 4076;     // 4800 (stage B + copy-out only)

    const int tid = threadIdx.x;
    const int n0 = blockIdx.x * 2;

    if (tid < 54)       xs[tid]      = x[n0 * 27 + tid];
    else if (tid < 108) ys[tid - 54] = y[n0 * 27 + tid - 54];
    for (int i = tid; i < 625; i += 256)            // Ts: 2500 floats
        ((float4*)Ts)[i] = ((const float4*)Tg)[i];
    for (int i = tid; i < 365; i += 256)            // Vs: 1460 floats (strided)
        ((float4*)Vs)[i] = ((const float4*)Vg)[i];
    __syncthreads();

    // P[row][100], pads zero
    for (int idx = tid; idx < 600; idx += 256) {
        int row = idx / 100, pq = idx % 100;
        float v = 0.f;
        int s, sp;
        if (decode2(pq, s, sp)) {
            int ni = row / 3, vv = row % 3;
            int a = (vv == 0) ? 1 : ((vv == 1) ? 2 : 0);
            int b = (vv == 0) ? 2 : ((vv == 1) ? 0 : 1);
            v = xs[ni * 27 + a * 9 + s] * ys[ni * 27 + b * 9 + sp]
              - xs[ni * 27 + b * 9 + s] * ys[ni * 27 + a * 9 + sp];
        }
        Ps[idx] = v;
    }
    __syncthreads();

    // Stage A (r11 verbatim): 150 threads, thread=(t,row); 25 f4-chunk dots
#define DOT4(c, accv) { float4 pv = P4[c], tv = T4[c];                      \
        accv = fmaf(pv.x, tv.x, accv); accv = fmaf(pv.y, tv.y, accv);       \
        accv = fmaf(pv.z, tv.z, accv); accv = fmaf(pv.w, tv.w, accv); }
    if (tid < 150) {
        int t = tid / 6, row = tid % 6;
        const float4* P4 = (const float4*)(Ps + row * 100);
        const float4* T4 = (const float4*)(Ts + t * 100);
        float a0 = 0.f, a1 = 0.f, a2 = 0.f, a3 = 0.f, a4 = 0.f,
              a5 = 0.f, a6 = 0.f, a7 = 0.f, a8 = 0.f;
        DOT4(0, a0)
        DOT4(1, a1)
        DOT4(2, a2)  DOT4(3, a2)
        DOT4(4, a3)
        DOT4(5, a4)  DOT4(6, a4)  DOT4(7, a4)
        DOT4(8, a5)  DOT4(9, a5)  DOT4(10, a5) DOT4(11, a5)
        DOT4(12, a6) DOT4(13, a6)
        DOT4(14, a7) DOT4(15, a7) DOT4(16, a7) DOT4(17, a7)
        DOT4(18, a8) DOT4(19, a8) DOT4(20, a8) DOT4(21, a8)
        DOT4(22, a8) DOT4(23, a8) DOT4(24, a8)
        float* zp = Z + row * 300 + t * 12;
        *(float4*)zp       = make_float4(a0, a1, a2, a3);
        *(float4*)(zp + 4) = make_float4(a4, a5, a6, a7);
        zp[8] = a8;
    }
#undef DOT4
    __syncthreads();
    // ---- Ts DEAD from here; Zout (overlaying it) becomes live ----

    // Stage B (NEW): 200 threads, thread = (t = tid>>3, dq = tid&7).
    // Hoist 9 V-f4 once; uniform 6-row loop: 2f4+1s Z-read (disjoint bank
    // spans across the 8 t-groups of a wave), 36 FMA, 4 Zout writes.
    if (tid < 200) {
        const int t = tid >> 3, dq = tid & 7;
        const int lt = (t >= 16) ? 4 : (t >= 9) ? 3 : (t >= 4) ? 2
                     : (t >= 1) ? 1 : 0;
        const float* vb = Vs + lt * 292 + dq * 4;
        const float4 w0 = *(const float4*)(vb +   0);
        const float4 w1 = *(const float4*)(vb +  32);
        const float4 w2 = *(const float4*)(vb +  64);
        const float4 w3 = *(const float4*)(vb +  96);
        const float4 w4 = *(const float4*)(vb + 128);
        const float4 w5 = *(const float4*)(vb + 160);
        const float4 w6 = *(const float4*)(vb + 192);
        const float4 w7 = *(const float4*)(vb + 224);
        const float4 w8 = *(const float4*)(vb + 256);
#pragma unroll
        for (int row = 0; row < 6; ++row) {
            const float* zp = Z + row * 300 + t * 12;
            const float4 za = *(const float4*)zp;
            const float4 zb = *(const float4*)(zp + 4);
            const float z8 = zp[8];
            float o0 = z8 * w8.x, o1 = z8 * w8.y, o2 = z8 * w8.z, o3 = z8 * w8.w;
            o0 = fmaf(za.x, w0.x, o0); o1 = fmaf(za.x, w0.y, o1);
            o2 = fmaf(za.x, w0.z, o2); o3 = fmaf(za.x, w0.w, o3);
            o0 = fmaf(za.y, w1.x, o0); o1 = fmaf(za.y, w1.y, o1);
            o2 = fmaf(za.y, w1.z, o2); o3 = fmaf(za.y, w1.w, o3);
            o0 = fmaf(za.z, w2.x, o0); o1 = fmaf(za.z, w2.y, o1);
            o2 = fmaf(za.z, w2.z, o2); o3 = fmaf(za.z, w2.w, o3);
            o0 = fmaf(za.w, w3.x, o0); o1 = fmaf(za.w, w3.y, o1);
            o2 = fmaf(za.w, w3.z, o2); o3 = fmaf(za.w, w3.w, o3);
            o0 = fmaf(zb.x, w4.x, o0); o1 = fmaf(zb.x, w4.y, o1);
            o2 = fmaf(zb.x, w4.z, o2); o3 = fmaf(zb.x, w4.w, o3);
            o0 = fmaf(zb.y, w5.x, o0); o1 = fmaf(zb.y, w5.y, o1);
            o2 = fmaf(zb.y, w5.z, o2); o3 = fmaf(zb.y, w5.w, o3);
            o0 = fmaf(zb.z, w6.x, o0); o1 = fmaf(zb.z, w6.y, o1);
            o2 = fmaf(zb.z, w6.z, o2); o3 = fmaf(zb.z, w6.w, o3);
            o0 = fmaf(zb.w, w7.x, o0); o1 = fmaf(zb.w, w7.y, o1);
            o2 = fmaf(zb.w, w7.z, o2); o3 = fmaf(zb.w, w7.w, o3);
            const int zo = (row / 3) * 2400 + (row % 3) * 25 + dq * 300 + t;
            Zout[zo      ] = o0;
            Zout[zo +  75] = o1;
            Zout[zo + 150] = o2;
            Zout[zo + 225] = o3;
        }
    }
    __syncthreads();

    // coalesced copy-out: 4800 floats = 1200 float4, contiguous per block
    float4* og = (float4*)(out + (size_t)n0 * 2400);
    const float4* zo4 = (const float4*)Zout;
    for (int i = tid; i < 1200; i += 256) og[i] = zo4[i];
}

extern "C" void kernel_launch(void* const* d_in, const int* in_sizes, int n_in,
                              void* d_out, int out_size, void* d_ws, size_t ws_size,
                              hipStream_t stream) {
    const float* x    = (const float*)d_in[0];
    const float* y    = (const float*)d_in[1];
    const float* Wx   = (const float*)d_in[2];
    const float* Wy   = (const float*)d_in[3];
    const float* Wz   = (const float*)d_in[4];
    const float* Yin  = (const float*)d_in[5];
    const float* Yout = (const float*)d_in[6];
    const float* wq   = (const float*)d_in[7];
    float* out = (float*)d_out;

    float* Tg = (float*)d_ws;        // 25*100 = 2500 floats
    float* Vg = Tg + 2500;           // 5*292 = 1460 floats (16B-aligned)

    precomp<<<631, 256, 0, stream>>>(Wx, Wy, Wz, Yin, Yout, wq, Tg, Vg);
    gaunt_main<<<1024, 256, 0, stream>>>(x, y, Tg, Vg, out);
}